// Round 1
// baseline (102.000 us; speedup 1.0000x reference)
//
#include <hip/hip_runtime.h>

// Problem constants (from reference setup_inputs)
constexpr int Bc = 4, Cc = 64, Tc = 16, Nc = 256, Hc = 128, Wc = 128;
constexpr int HW  = Hc * Wc;       // 16384
constexpr int THW = Tc * HW;       // 262144
constexpr int NPTS = Bc * Tc * Nc; // 16384

// pair kernel split: each block handles half the m-range of one slice pair
constexpr int SPLIT = 2;
constexpr int MPB   = Nc / SPLIT;  // 128

// ws float layout: [0] mse_sum, [1..4] se[lag], [5..8] cnt[lag] (u32 bits), [16..] sel

__global__ void init_acc(float* ws) {
    if (threadIdx.x < 16) ws[threadIdx.x] = 0.0f;
}

__global__ void gather_norm(const float* __restrict__ feat,
                            const int* __restrict__ coord,
                            float* __restrict__ sel) {
    int tid = blockIdx.x * 256 + threadIdx.x;
    int p = tid >> 6;       // point id 0..16383
    int c = tid & 63;       // channel
    int b = p >> 12;        // p / (T*N)
    int t = (p >> 8) & 15;  // (p % (T*N)) / N
    int x = coord[2 * p + 0];
    int y = coord[2 * p + 1];
    float v = 0.0f;
    if (x >= 0 && y >= 0) {
        v = feat[(size_t)(b * Cc + c) * THW + t * HW + y * Wc + x];
    }
    float sq = v * v;
    #pragma unroll
    for (int off = 32; off; off >>= 1) sq += __shfl_xor(sq, off);
    float inv = 1.0f / fmaxf(sqrtf(sq), 1e-12f);
    sel[(size_t)p * Cc + c] = v * inv;
}

__global__ void mse_red(const float* __restrict__ pred,
                        const float* __restrict__ tgt,
                        float* __restrict__ acc) {
    int i = blockIdx.x * 256 + threadIdx.x;   // 16384 threads, 4 elems each
    float4 p = ((const float4*)pred)[i];
    float4 q = ((const float4*)tgt)[i];
    float dx = p.x - q.x, dy = p.y - q.y, dz = p.z - q.z, dw = p.w - q.w;
    float s = dx * dx + dy * dy + dz * dz + dw * dw;
    #pragma unroll
    for (int off = 32; off; off >>= 1) s += __shfl_xor(s, off);
    if ((threadIdx.x & 63) == 0) atomicAdd(acc, s);
}

__global__ __launch_bounds__(256) void pair_loss(
        const float* __restrict__ sel,
        const int* __restrict__ coord,
        const int* __restrict__ label,
        float* __restrict__ acc) {
    __shared__ float sB[MPB * Cc];     // 32 KB
    __shared__ int sbx[MPB], sby[MPB], slb[MPB];
    __shared__ float wse[4];
    __shared__ unsigned wcnt[4];

    int blk   = blockIdx.x;
    int slice = blk / SPLIT;
    int half  = blk % SPLIT;

    int lag, base;
    if (slice < 64)       { lag = 0; base = 0;   }
    else if (slice < 124) { lag = 1; base = 64;  }
    else if (slice < 180) { lag = 2; base = 124; }
    else                  { lag = 3; base = 180; }
    int idx = slice - base;
    int ns  = Tc - lag;
    int b   = idx / ns;
    int ta  = idx % ns;
    int tb  = ta + lag;
    int thr2 = (lag <= 1) ? 625 : (lag == 2 ? 900 : 1225);

    int t  = threadIdx.x;
    int pA = (b * Tc + ta) * Nc;              // + n (= t)
    int pB = (b * Tc + tb) * Nc + half * MPB; // + local m

    // stage B rows (coalesced)
    {
        const float4* src = (const float4*)(sel + (size_t)pB * Cc);
        float4* dst = (float4*)sB;
        #pragma unroll
        for (int k = t; k < MPB * Cc / 4; k += 256) dst[k] = src[k];
        if (t < MPB) {
            sbx[t] = coord[2 * (pB + t) + 0];
            sby[t] = coord[2 * (pB + t) + 1];
            slb[t] = label[pB + t];
        }
    }
    __syncthreads();

    // A row in registers
    float a[Cc];
    {
        const float4* as = (const float4*)(sel + (size_t)(pA + t) * Cc);
        #pragma unroll
        for (int k = 0; k < 16; k++) ((float4*)a)[k] = as[k];
    }
    int ax = coord[2 * (pA + t) + 0];
    int ay = coord[2 * (pA + t) + 1];
    int la = label[pA + t];
    bool padA = ax < 0;

    float se = 0.0f;
    unsigned cnt = 0;
    for (int m = 0; m < MPB; m++) {
        const float4* brow = (const float4*)(sB + m * Cc);
        float d0 = 0.f, d1 = 0.f, d2 = 0.f, d3 = 0.f;
        #pragma unroll
        for (int k = 0; k < 16; k++) {
            float4 bv = brow[k];
            d0 = fmaf(a[4 * k + 0], bv.x, d0);
            d1 = fmaf(a[4 * k + 1], bv.y, d1);
            d2 = fmaf(a[4 * k + 2], bv.z, d2);
            d3 = fmaf(a[4 * k + 3], bv.w, d3);
        }
        float dot = (d0 + d1) + (d2 + d3);
        int ddx = ax - sbx[m];
        int ddy = ay - sby[m];
        int dd  = ddx * ddx + ddy * ddy;
        bool cond = (dd < thr2) && !padA && (sbx[m] >= 0);
        if (cond) {
            float lbl = (la == slb[m]) ? 1.0f : 0.0f;
            float df = dot - lbl;
            se += df * df;
            cnt++;
        }
    }

    // reduce within wave, then across the 4 waves
    #pragma unroll
    for (int off = 32; off; off >>= 1) {
        se  += __shfl_xor(se, off);
        cnt += __shfl_xor(cnt, off);
    }
    int w = t >> 6;
    if ((t & 63) == 0) { wse[w] = se; wcnt[w] = cnt; }
    __syncthreads();
    if (t == 0) {
        float S = (wse[0] + wse[1]) + (wse[2] + wse[3]);
        unsigned Ct = wcnt[0] + wcnt[1] + wcnt[2] + wcnt[3];
        atomicAdd(&acc[1 + lag], S);
        atomicAdd(&((unsigned*)acc)[5 + lag], Ct);
    }
}

__global__ void finalize(const float* __restrict__ ws, float* __restrict__ out) {
    float mse = ws[0] / 65536.0f;
    const unsigned* cw = (const unsigned*)ws;
    float l = 0.0f;
    #pragma unroll
    for (int i = 0; i < 4; i++) {
        unsigned c = cw[5 + i];
        float denom = (float)(c > 0 ? c : 1u);
        l += ws[1 + i] / denom;
    }
    out[0] = mse + 0.25f * l;
}

extern "C" void kernel_launch(void* const* d_in, const int* in_sizes, int n_in,
                              void* d_out, int out_size, void* d_ws, size_t ws_size,
                              hipStream_t stream) {
    const float* predicts = (const float*)d_in[0];
    const float* feature  = (const float*)d_in[1];
    const int*   coord    = (const int*)d_in[2];
    const float* targets  = (const float*)d_in[3];
    const int*   label    = (const int*)d_in[4];
    float* out = (float*)d_out;
    float* ws  = (float*)d_ws;
    float* sel = ws + 16;

    hipLaunchKernelGGL(init_acc, dim3(1), dim3(64), 0, stream, ws);
    hipLaunchKernelGGL(gather_norm, dim3(NPTS * 64 / 256), dim3(256), 0, stream,
                       feature, coord, sel);
    hipLaunchKernelGGL(mse_red, dim3(64), dim3(256), 0, stream,
                       predicts, targets, ws);
    hipLaunchKernelGGL(pair_loss, dim3(232 * SPLIT), dim3(256), 0, stream,
                       sel, coord, label, ws);
    hipLaunchKernelGGL(finalize, dim3(1), dim3(1), 0, stream, ws, out);
}

// Round 2
// 44.046 us; speedup vs baseline: 2.3158x; 2.3158x over previous
//
#include <hip/hip_runtime.h>
#include <hip/hip_bf16.h>

constexpr int Bc = 4, Cc = 64, Tc = 16, Nc = 256, Hc = 128, Wc = 128;
constexpr int HW  = Hc * Wc;       // 16384
constexpr int THW = Tc * HW;       // 262144
constexpr int NPTS = Bc * Tc * Nc; // 16384

constexpr int GATHER_BLOCKS = NPTS * 64 / 256; // 4096
constexpr int MSE_BLOCKS    = 64;
constexpr int NSLICE = 232;                    // 64+60+56+52
constexpr int SPLIT  = 2;                      // col halves per slice
constexpr int PAIR_BLOCKS = NSLICE * SPLIT;    // 464

// ws float layout:
//   [0..63]    mse partials (per mse block)
//   [64..527]  se partials  (per pair block)
//   [528..991] cnt partials (as float, per pair block)
//   [1024..]   sel as bf16, NPTS x 64  (2 MB)

typedef short short8 __attribute__((ext_vector_type(8)));
typedef float f32x4  __attribute__((ext_vector_type(4)));

__global__ __launch_bounds__(256) void k1_gather_mse(
        const float* __restrict__ feat,
        const int*   __restrict__ coord,
        const float* __restrict__ pred,
        const float* __restrict__ tgt,
        float* __restrict__ ws) {
    __shared__ float ls[4];
    __hip_bfloat16* selb = (__hip_bfloat16*)(ws + 1024);
    int blk = blockIdx.x;
    int t   = threadIdx.x;

    if (blk < GATHER_BLOCKS) {
        int tid = blk * 256 + t;
        int p = tid >> 6;       // point id
        int c = tid & 63;       // channel
        int b = p >> 12;
        int tt = (p >> 8) & 15;
        int x = coord[2 * p + 0];
        int y = coord[2 * p + 1];
        float v = 0.0f;
        if (x >= 0 && y >= 0)
            v = feat[(size_t)(b * Cc + c) * THW + tt * HW + y * Wc + x];
        float sq = v * v;
        #pragma unroll
        for (int o = 32; o; o >>= 1) sq += __shfl_xor(sq, o);
        float inv = 1.0f / fmaxf(sqrtf(sq), 1e-12f);
        selb[(size_t)p * 64 + c] = __float2bfloat16(v * inv);
    } else {
        int i = (blk - GATHER_BLOCKS) * 256 + t;
        float4 p4 = ((const float4*)pred)[i];
        float4 q4 = ((const float4*)tgt)[i];
        float dx = p4.x - q4.x, dy = p4.y - q4.y;
        float dz = p4.z - q4.z, dw = p4.w - q4.w;
        float s = dx * dx + dy * dy + dz * dz + dw * dw;
        #pragma unroll
        for (int o = 32; o; o >>= 1) s += __shfl_xor(s, o);
        if ((t & 63) == 0) ls[t >> 6] = s;
        __syncthreads();
        if (t == 0)
            ws[blk - GATHER_BLOCKS] = (ls[0] + ls[1]) + (ls[2] + ls[3]);
    }
}

__global__ __launch_bounds__(512) void k2_pair(
        const int* __restrict__ coord,
        const int* __restrict__ label,
        float* __restrict__ ws) {
    const short8* selb = (const short8*)(ws + 1024); // 8 chunks of 8 bf16 per row

    int blk   = blockIdx.x;
    int slice = blk >> 1;
    int half  = blk & 1;

    int lag, base, thr2;
    if (slice < 64)       { lag = 0; base = 0;   thr2 = 625;  }
    else if (slice < 124) { lag = 1; base = 64;  thr2 = 625;  }
    else if (slice < 180) { lag = 2; base = 124; thr2 = 900;  }
    else                  { lag = 3; base = 180; thr2 = 1225; }
    int idx = slice - base;
    int ns  = Tc - lag;
    int b   = idx / ns;
    int ta  = idx % ns;
    int tb  = ta + lag;
    int pA  = (b * Tc + ta) * Nc;
    int pB  = (b * Tc + tb) * Nc;

    int t    = threadIdx.x;
    int w    = t >> 6;
    int lane = t & 63;
    int lr   = lane & 15;
    int kb   = lane >> 4;   // 0..3

    int rb0 = w * 32;
    int rb1 = w * 32 + 16;

    // A fragments (rows pA+rb+lr, channel chunks kb and 4+kb)
    const short8* arow0 = selb + (size_t)(pA + rb0 + lr) * 8;
    const short8* arow1 = selb + (size_t)(pA + rb1 + lr) * 8;
    short8 a00 = arow0[kb],     a01 = arow0[4 + kb];
    short8 a10 = arow1[kb],     a11 = arow1[4 + kb];

    // per-lane A-side epilogue data: rows rb + kb*4 + i
    int ax0[4], ay0[4], la0[4], ax1[4], ay1[4], la1[4];
    #pragma unroll
    for (int i = 0; i < 4; i++) {
        int r0 = pA + rb0 + kb * 4 + i;
        int r1 = pA + rb1 + kb * 4 + i;
        ax0[i] = coord[2 * r0]; ay0[i] = coord[2 * r0 + 1]; la0[i] = label[r0];
        ax1[i] = coord[2 * r1]; ay1[i] = coord[2 * r1 + 1]; la1[i] = label[r1];
    }

    float se = 0.0f;
    int cnt = 0;

    for (int cb = 0; cb < 8; cb++) {
        int m  = half * 128 + cb * 16;
        int pm = pB + m + lr;
        const short8* brow = selb + (size_t)pm * 8;
        short8 b0 = brow[kb], b1 = brow[4 + kb];
        int bx = coord[2 * pm], by = coord[2 * pm + 1], lb = label[pm];
        bool bok = bx >= 0;

        f32x4 acc0 = {0.f, 0.f, 0.f, 0.f};
        acc0 = __builtin_amdgcn_mfma_f32_16x16x32_bf16(a00, b0, acc0, 0, 0, 0);
        acc0 = __builtin_amdgcn_mfma_f32_16x16x32_bf16(a01, b1, acc0, 0, 0, 0);
        #pragma unroll
        for (int i = 0; i < 4; i++) {
            int ddx = ax0[i] - bx, ddy = ay0[i] - by;
            int dd  = ddx * ddx + ddy * ddy;
            bool cond = (dd < thr2) && (ax0[i] >= 0) && bok;
            float lbl = (la0[i] == lb) ? 1.0f : 0.0f;
            float df  = acc0[i] - lbl;
            df = cond ? df : 0.0f;
            se = fmaf(df, df, se);
            cnt += cond ? 1 : 0;
        }

        f32x4 acc1 = {0.f, 0.f, 0.f, 0.f};
        acc1 = __builtin_amdgcn_mfma_f32_16x16x32_bf16(a10, b0, acc1, 0, 0, 0);
        acc1 = __builtin_amdgcn_mfma_f32_16x16x32_bf16(a11, b1, acc1, 0, 0, 0);
        #pragma unroll
        for (int i = 0; i < 4; i++) {
            int ddx = ax1[i] - bx, ddy = ay1[i] - by;
            int dd  = ddx * ddx + ddy * ddy;
            bool cond = (dd < thr2) && (ax1[i] >= 0) && bok;
            float lbl = (la1[i] == lb) ? 1.0f : 0.0f;
            float df  = acc1[i] - lbl;
            df = cond ? df : 0.0f;
            se = fmaf(df, df, se);
            cnt += cond ? 1 : 0;
        }
    }

    #pragma unroll
    for (int o = 32; o; o >>= 1) {
        se  += __shfl_xor(se, o);
        cnt += __shfl_xor(cnt, o);
    }
    __shared__ float wse[8];
    __shared__ int   wcnt[8];
    if (lane == 0) { wse[w] = se; wcnt[w] = cnt; }
    __syncthreads();
    if (t == 0) {
        float S = 0.0f; int C = 0;
        #pragma unroll
        for (int i = 0; i < 8; i++) { S += wse[i]; C += wcnt[i]; }
        ws[64 + blk]  = S;
        ws[528 + blk] = (float)C;
    }
}

__global__ __launch_bounds__(256) void k3_final(
        const float* __restrict__ ws,
        float* __restrict__ out) {
    int t = threadIdx.x;
    int w = t >> 6, lane = t & 63;

    float ms = (t < 64) ? ws[t] : 0.0f;
    float se4[4] = {0, 0, 0, 0};
    float cn4[4] = {0, 0, 0, 0};
    for (int i = t; i < PAIR_BLOCKS; i += 256) {
        int slice = i >> 1;
        int lg = (slice < 64) ? 0 : (slice < 124) ? 1 : (slice < 180) ? 2 : 3;
        se4[lg] += ws[64 + i];
        cn4[lg] += ws[528 + i];
    }
    #pragma unroll
    for (int o = 32; o; o >>= 1) {
        ms += __shfl_xor(ms, o);
        #pragma unroll
        for (int lg = 0; lg < 4; lg++) {
            se4[lg] += __shfl_xor(se4[lg], o);
            cn4[lg] += __shfl_xor(cn4[lg], o);
        }
    }
    __shared__ float sh[4][9];
    if (lane == 0) {
        sh[w][0] = ms;
        #pragma unroll
        for (int lg = 0; lg < 4; lg++) {
            sh[w][1 + lg] = se4[lg];
            sh[w][5 + lg] = cn4[lg];
        }
    }
    __syncthreads();
    if (t == 0) {
        float mse = 0.0f;
        float se[4] = {0, 0, 0, 0}, cn[4] = {0, 0, 0, 0};
        for (int i = 0; i < 4; i++) {
            mse += sh[i][0];
            for (int lg = 0; lg < 4; lg++) {
                se[lg] += sh[i][1 + lg];
                cn[lg] += sh[i][5 + lg];
            }
        }
        float l = 0.0f;
        for (int lg = 0; lg < 4; lg++)
            l += se[lg] / fmaxf(cn[lg], 1.0f);
        out[0] = mse / 65536.0f + 0.25f * l;
    }
}

extern "C" void kernel_launch(void* const* d_in, const int* in_sizes, int n_in,
                              void* d_out, int out_size, void* d_ws, size_t ws_size,
                              hipStream_t stream) {
    const float* predicts = (const float*)d_in[0];
    const float* feature  = (const float*)d_in[1];
    const int*   coord    = (const int*)d_in[2];
    const float* targets  = (const float*)d_in[3];
    const int*   label    = (const int*)d_in[4];
    float* out = (float*)d_out;
    float* ws  = (float*)d_ws;

    hipLaunchKernelGGL(k1_gather_mse, dim3(GATHER_BLOCKS + MSE_BLOCKS), dim3(256),
                       0, stream, feature, coord, predicts, targets, ws);
    hipLaunchKernelGGL(k2_pair, dim3(PAIR_BLOCKS), dim3(512), 0, stream,
                       coord, label, ws);
    hipLaunchKernelGGL(k3_final, dim3(1), dim3(256), 0, stream, ws, out);
}